// Round 5
// baseline (148.652 us; speedup 1.0000x reference)
//
#include <hip/hip_runtime.h>

#define NN 4096
#define DIM 128
#define TN 32            // q-rows per block
#define TM 64            // m-tile size
#define NSPLIT 4         // split-m factor
#define NTILES 16        // tiles per block (64 global tiles / 4)

typedef __attribute__((ext_vector_type(8))) short bf16x8;
typedef __attribute__((ext_vector_type(4))) float f32x4;

#define HRS 136                        // Hrow/Q stride (ushorts, 272 B = 17x16B)
#define HCS 72                         // Hcol stride (ushorts, 144 B = 9x16B)
#define HROW_USH (TM * HRS)            // 64*136 = 8704
#define HCOL_USH (128 * HCS)           // 128*72 = 9216
#define TILE_USH (HROW_USH + HCOL_USH) // 17920 ushorts = 35840 B
#define TILE_CHUNKS 35                 // 35840 / 1024
#define PST 72                         // P row stride (ushorts)

__device__ inline unsigned short f2bf(float x) {
    union { float f; unsigned u; } v; v.f = x;
    unsigned r = v.u + 0x7FFFu + ((v.u >> 16) & 1u);
    return (unsigned short)(r >> 16);
}

// async global->LDS DMA, 16 B/lane, dest = wave-uniform base + lane*16
__device__ inline void dma16(const void* g, void* l) {
    __builtin_amdgcn_global_load_lds(
        (const __attribute__((address_space(1))) void*)g,
        (__attribute__((address_space(3))) void*)l,
        16, 0, 0);
}

// ---- prep (512 blocks = 64 tiles x 8 slices):
//      hidden fp32 -> Hpack[64 tiles][Hrow 64x136 | Hcol 128x72] bf16 ----
__global__ __launch_bounds__(256) void prep_pack_kernel(
    const float* __restrict__ hidden,
    unsigned short* __restrict__ Hpack)
{
    __shared__ unsigned short T[16][HCS];   // transpose slice [d][m]
    const int tid = threadIdx.x;
    const int t0  = blockIdx.x >> 3;   // tile 0..63
    const int s   = blockIdx.x & 7;    // slice 0..7
    const int m0  = t0 * TM;
    unsigned short* rowdst = Hpack + (size_t)t0 * TILE_USH;
    unsigned short* coldst = rowdst + HROW_USH;

    // rows part: rows [8s, 8s+8) x 128 d -> rowdst
    {
        int row = tid >> 5;            // 0..7
        int c4  = (tid & 31) * 4;      // 0..124
        float4 v = *(const float4*)(hidden + (size_t)(m0 + 8 * s + row) * DIM + c4);
        ushort4 o;
        o.x = f2bf(v.x); o.y = f2bf(v.y); o.z = f2bf(v.z); o.w = f2bf(v.w);
        *(ushort4*)(rowdst + (8 * s + row) * HRS + c4) = o;
    }
    // cols part: d in [16s, 16s+16) x 64 m -> T (transposed)
    {
        int m  = tid >> 2;             // 0..63
        int dc = (tid & 3) * 4;        // 0..12
        float4 v = *(const float4*)(hidden + (size_t)(m0 + m) * DIM + 16 * s + dc);
        T[dc + 0][m] = f2bf(v.x);
        T[dc + 1][m] = f2bf(v.y);
        T[dc + 2][m] = f2bf(v.z);
        T[dc + 3][m] = f2bf(v.w);
    }
    __syncthreads();
    if (tid < 128) {
        int d  = tid >> 3;             // 0..15
        int c8 = (tid & 7) * 8;        // m chunk of 8
        uint4 v = *(const uint4*)(&T[d][c8]);
        *(uint4*)(coldst + (16 * s + d) * HCS + c8) = v;
    }
}

// ---- main: TN=32, 8 waves = 2 row-groups x 4 slices (16-wide QK / 32-wide PV),
//      512 threads, LDS 76.8 KB -> 2 blocks/CU = 16 waves/CU (4/EU).
//      NEW (round 5): ANTIPHASE TILE ROTATION. Co-resident blocks are blk and
//      blk+256 (8-XCD round-robin, 512 blocks / 256 CUs); both previously ran
//      the identical barrier cadence -> all waves hit the MFMA phase together,
//      then the VALU phase together (MfmaUtil 16% + VALUBusy 27%, nothing
//      saturated, and 2x occupancy of R0 gained 0%). Blocks with blk>=256 now
//      start 8 tiles ahead (tg = gt0 + ((tile+ph)&15)) so the two blocks'
//      MFMA/VALU/DMA phases interleave instead of colliding.
//      Resource config kept byte-identical to R4 (proven 2-blocks/CU). ----
__global__ __launch_bounds__(512)
__attribute__((amdgpu_waves_per_eu(4, 4)))
void gat_flash_kernel(
    const float* __restrict__ hidden,        // fp32 (Q only)
    const unsigned short* __restrict__ Hpack,
    const int*   __restrict__ adj,           // [NN][NN] int32
    const float* __restrict__ W,
    const float* __restrict__ bvec,
    float*       __restrict__ Opart,         // [512][TN][DIM]
    float*       __restrict__ lpart)         // [512][TN]
{
    __shared__ __align__(16) unsigned short HH[2][TILE_USH];   // 71680 B
    __shared__ __align__(16) unsigned short Plc[TN * PST];     // 4608 B
    __shared__ float redsum[8][16];                            // 512 B

    const int tid  = threadIdx.x;
    const int w    = tid >> 6;         // 0..7
    const int lane = tid & 63;
    const int g    = lane >> 4;
    const int l15  = lane & 15;
    const int blk  = blockIdx.x;
    const int nbr  = blk >> 2;         // 0..127 row-group of 32
    const int q4   = blk & 3;
    const int n0   = nbr * TN;
    const int gt0  = q4 * NTILES;      // first global tile (of 64)
    const int ph   = ((blk >> 8) & 1) * (NTILES / 2);  // antiphase offset
    const int rg   = w >> 2;           // 0..1: 16-row group
    const int msw  = w & 3;            // 0..3: 16-wide m-slice (QK) / 32-wide d-slice (PV)
    const int lofs = lane * 16;

    const float b0 = bvec[0], b1 = bvec[1], b2 = bvec[2], b3 = bvec[3];

    const int tg_first = gt0 + ph;     // rotated tile for iteration 0 (ph < NTILES)

    // ---- prologue: DMA tile tg_first -> HH[0] (overlaps Q compute below) ----
    {
        const char* src = (const char*)(Hpack + (size_t)tg_first * TILE_USH);
        char* dst = (char*)&HH[0][0];
        #pragma unroll
        for (int it = 0; it < 5; ++it) {
            int chunk = it * 8 + w;
            if (chunk < TILE_CHUNKS)
                dma16(src + chunk * 1024 + lofs, dst + chunk * 1024);
        }
    }
    // Q into HH[1]: 128 rows (k*32 + r) x 128 d, stride HRS (17408 <= 17920)
    {
        #pragma unroll
        for (int it = 0; it < 2; ++it) {
            int idx = tid + 512 * it;      // 0..1023
            int row = idx >> 3;            // 0..127 = k*32 + r
            int c16 = (idx & 7) * 16;
            int k = row >> 5, r = row & 31;
            const float* hrow = hidden + (size_t)(n0 + r) * DIM + c16;
            const float* wrow = W + k * DIM + c16;
            unsigned short* qdst = &HH[1][row * HRS + c16];
            #pragma unroll
            for (int c = 0; c < 4; ++c) {
                float4 hv = *(const float4*)(hrow + 4 * c);
                float4 wv = *(const float4*)(wrow + 4 * c);
                ushort4 o;
                o.x = f2bf(hv.x * wv.x); o.y = f2bf(hv.y * wv.y);
                o.z = f2bf(hv.z * wv.z); o.w = f2bf(hv.w * wv.w);
                *(ushort4*)(qdst + 4 * c) = o;
            }
        }
    }
    __syncthreads();   // drains tile-0 DMA (vmcnt) + Q LDS writes (lgkm)

    // A-fragments for this wave's 16 rows; HH[1] becomes a staging buffer
    bf16x8 Af[4][4];
    #pragma unroll
    for (int k = 0; k < 4; ++k)
        #pragma unroll
        for (int ks = 0; ks < 4; ++ks)
            Af[k][ks] = *(const bf16x8*)&HH[1][(k * 32 + rg * 16 + l15) * HRS + ks * 32 + 8 * g];
    __syncthreads();   // Af reads drained before next-tile DMA may write HH[1]

    float lrow[4] = {0.f, 0.f, 0.f, 0.f};
    f32x4 Oacc[2];
    #pragma unroll
    for (int dt = 0; dt < 2; ++dt) Oacc[dt] = (f32x4){0.f, 0.f, 0.f, 0.f};

    // direct adj codes for first (rotated) tile: 4 coalesced int loads/lane
    const size_t arow = (size_t)(n0 + rg * 16 + 4 * g) * NN;   // row of t=0
    int avc[4], avn[4];
    #pragma unroll
    for (int t = 0; t < 4; ++t)
        avc[t] = adj[arow + (size_t)t * NN + tg_first * TM + msw * 16 + l15];

    for (int tile = 0; tile < NTILES; ++tile) {
        const int cur = tile & 1;
        const int nxt = cur ^ 1;
        const int tgn = gt0 + ((tile + 1 + ph) & (NTILES - 1));   // next rotated tile

        // ---- issue next-tile DMA; stays in flight all tile ----
        if (tile + 1 < NTILES) {
            const char* src = (const char*)(Hpack + (size_t)tgn * TILE_USH);
            char* dst = (char*)&HH[nxt][0];
            #pragma unroll
            for (int it = 0; it < 5; ++it) {
                int chunk = it * 8 + w;
                if (chunk < TILE_CHUNKS)
                    dma16(src + chunk * 1024 + lofs, dst + chunk * 1024);
            }
        }

        // ---- QK: S[k] over 16-wide m-slice for rows rg*16..+16 ----
        f32x4 S[4];
        #pragma unroll
        for (int k = 0; k < 4; ++k) S[k] = (f32x4){0.f, 0.f, 0.f, 0.f};
        #pragma unroll
        for (int ks = 0; ks < 4; ++ks) {
            bf16x8 B = *(const bf16x8*)&HH[cur][(msw * 16 + l15) * HRS + ks * 32 + 8 * g];
            #pragma unroll
            for (int k = 0; k < 4; ++k)
                S[k] = __builtin_amdgcn_mfma_f32_16x16x32_bf16(Af[k][ks], B, S[k], 0, 0, 0);
        }

        // ---- select + leakyrelu + exp (no-max softmax; scores bounded) ----
        #pragma unroll
        for (int t = 0; t < 4; ++t) {
            int a = avc[t];
            float s = S[0][t] + b0;
            s = (a == 2) ? S[1][t] + b1 : s;
            s = (a == 3) ? S[2][t] + b2 : s;
            s = (a == 4) ? S[3][t] + b3 : s;
            float e = fmaxf(s, 0.2f * s);
            float p = __expf(e);
            p = (a == 0) ? 0.f : p;
            lrow[t] += p;
            Plc[(rg * 16 + 4 * g + t) * PST + msw * 16 + l15] = f2bf(p);
        }

        // ---- adj prefetch for next tile (latency hidden by PV + next QK) ----
        if (tile + 1 < NTILES) {
            #pragma unroll
            for (int t = 0; t < 4; ++t)
                avn[t] = adj[arow + (size_t)t * NN + (size_t)tgn * TM + msw * 16 + l15];
        }

        // ---- P-ready barrier: LDS-only drain; DMA stays in flight ----
        asm volatile("s_waitcnt lgkmcnt(0)\n\ts_barrier" ::: "memory");

        // ---- PV: rows rg*16..+16, d-slice [msw*32, +32), K=64 ----
        #pragma unroll
        for (int kc = 0; kc < 2; ++kc) {
            bf16x8 Pa = *(const bf16x8*)&Plc[(rg * 16 + l15) * PST + kc * 32 + 8 * g];
            #pragma unroll
            for (int dt = 0; dt < 2; ++dt) {
                bf16x8 Bv = *(const bf16x8*)&HH[cur][HROW_USH + (msw * 32 + dt * 16 + l15) * HCS + kc * 32 + 8 * g];
                Oacc[dt] = __builtin_amdgcn_mfma_f32_16x16x32_bf16(Pa, Bv, Oacc[dt], 0, 0, 0);
            }
        }

        #pragma unroll
        for (int i = 0; i < 4; ++i) avc[i] = avn[i];
        __syncthreads();   // vmcnt(0) drain == "HH[nxt] staged"; buffer swap
    }

    // ---- epilogue: O is wave-disjoint (rg, msw) -> direct store ----
    #pragma unroll
    for (int t = 0; t < 4; ++t) {
        float v = lrow[t];
        v += __shfl_xor(v, 1); v += __shfl_xor(v, 2);
        v += __shfl_xor(v, 4); v += __shfl_xor(v, 8);
        if (l15 == 0) redsum[w][4 * g + t] = v;
    }
    __syncthreads();
    if (tid < TN) {
        int rg2 = tid >> 4, rr = tid & 15;
        lpart[blk * TN + tid] = redsum[rg2 * 4 + 0][rr] + redsum[rg2 * 4 + 1][rr]
                              + redsum[rg2 * 4 + 2][rr] + redsum[rg2 * 4 + 3][rr];
    }
    float* Ob = Opart + (size_t)blk * (TN * DIM);
    #pragma unroll
    for (int dt = 0; dt < 2; ++dt)
        #pragma unroll
        for (int t = 0; t < 4; ++t)
            Ob[(rg * 16 + 4 * g + t) * DIM + msw * 32 + dt * 16 + l15] = Oacc[dt][t];
}

// ---- combine the four m-quarters ----
__global__ __launch_bounds__(256) void combine_kernel(
    const float* __restrict__ Opart, const float* __restrict__ lpart,
    float* __restrict__ out)
{
    int idx = blockIdx.x * 256 + threadIdx.x;
    int r = idx >> 7, d = idx & 127;
    int nbr = r >> 5, rr = r & 31;
    float O = 0.f, l = 0.f;
    #pragma unroll
    for (int q = 0; q < NSPLIT; ++q) {
        O += Opart[(size_t)(nbr * NSPLIT + q) * (TN * DIM) + rr * 128 + d];
        l += lpart[(nbr * NSPLIT + q) * TN + rr];
    }
    out[idx] = O / l;
}

extern "C" void kernel_launch(void* const* d_in, const int* in_sizes, int n_in,
                              void* d_out, int out_size, void* d_ws, size_t ws_size,
                              hipStream_t stream) {
    const float* hidden = (const float*)d_in[0];
    const int*   adj    = (const int*)d_in[1];
    const float* W      = (const float*)d_in[2];
    const float* b      = (const float*)d_in[3];
    float* out = (float*)d_out;

    char* ws = (char*)d_ws;
    unsigned short* Hpack = (unsigned short*)ws;                 // 2.29 MB
    float* Opart = (float*)(ws + (4u << 20));                    // 512*32*128*4 = 8 MB
    float* lpart = (float*)(ws + (12u << 20));                   // 64 KB

    prep_pack_kernel<<<(NN / TM) * 8, 256, 0, stream>>>(hidden, Hpack);
    gat_flash_kernel<<<512, 512, 0, stream>>>(hidden, Hpack, adj, W, b, Opart, lpart);
    combine_kernel<<<NN * DIM / 256, 256, 0, stream>>>(Opart, lpart, out);
}

// Round 6
// 130.661 us; speedup vs baseline: 1.1377x; 1.1377x over previous
//
#include <hip/hip_runtime.h>

#define NN 4096
#define DIM 128
#define TN 64            // q-rows per block (4 waves x 16 rows)
#define TM 64            // m-tile size
#define NSPLIT 8         // split-m factor (atomic combine)
#define NTILES 8         // tiles per block (64 global tiles / 8)

typedef __attribute__((ext_vector_type(8))) short bf16x8;
typedef __attribute__((ext_vector_type(4))) float f32x4;

#define HRS 136                        // Hrow stride (ushorts, 272 B, 16B-mult)
#define HCS 72                         // Hcol stride (ushorts, 144 B, 16B-mult)
#define HROW_USH (TM * HRS)            // 64*136 = 8704
#define HCOL_USH (128 * HCS)           // 128*72 = 9216
#define TILE_USH (HROW_USH + HCOL_USH) // 17920 ushorts = 35840 B
#define TILE_CHUNKS 35                 // 35840 / 1024
#define PST 72                         // P scratch row stride (ushorts, 16B-mult)

__device__ inline unsigned short f2bf(float x) {
    union { float f; unsigned u; } v; v.f = x;
    unsigned r = v.u + 0x7FFFu + ((v.u >> 16) & 1u);
    return (unsigned short)(r >> 16);
}

// async global->LDS DMA, 16 B/lane, dest = wave-uniform base + lane*16
__device__ inline void dma16(const void* g, void* l) {
    __builtin_amdgcn_global_load_lds(
        (const __attribute__((address_space(1))) void*)g,
        (__attribute__((address_space(3))) void*)l,
        16, 0, 0);
}

// ---- prep (512 blocks = 64 tiles x 8 slices):
//      hidden fp32 -> Hpack[64 tiles][Hrow 64x136 | Hcol 128x72] bf16 ----
__global__ __launch_bounds__(256) void prep_pack_kernel(
    const float* __restrict__ hidden,
    unsigned short* __restrict__ Hpack)
{
    __shared__ unsigned short T[16][HCS];   // transpose slice [d][m]
    const int tid = threadIdx.x;
    const int t0  = blockIdx.x >> 3;   // tile 0..63
    const int s   = blockIdx.x & 7;    // slice 0..7
    const int m0  = t0 * TM;
    unsigned short* rowdst = Hpack + (size_t)t0 * TILE_USH;
    unsigned short* coldst = rowdst + HROW_USH;

    // rows part: rows [8s, 8s+8) x 128 d -> rowdst
    {
        int row = tid >> 5;            // 0..7
        int c4  = (tid & 31) * 4;      // 0..124
        float4 v = *(const float4*)(hidden + (size_t)(m0 + 8 * s + row) * DIM + c4);
        ushort4 o;
        o.x = f2bf(v.x); o.y = f2bf(v.y); o.z = f2bf(v.z); o.w = f2bf(v.w);
        *(ushort4*)(rowdst + (8 * s + row) * HRS + c4) = o;
    }
    // cols part: d in [16s, 16s+16) x 64 m -> T (transposed)
    {
        int m  = tid >> 2;             // 0..63
        int dc = (tid & 3) * 4;        // 0..12
        float4 v = *(const float4*)(hidden + (size_t)(m0 + m) * DIM + 16 * s + dc);
        T[dc + 0][m] = f2bf(v.x);
        T[dc + 1][m] = f2bf(v.y);
        T[dc + 2][m] = f2bf(v.z);
        T[dc + 3][m] = f2bf(v.w);
    }
    __syncthreads();
    if (tid < 128) {
        int d  = tid >> 3;             // 0..15
        int c8 = (tid & 7) * 8;        // m chunk of 8
        uint4 v = *(const uint4*)(&T[d][c8]);
        *(uint4*)(coldst + (16 * s + d) * HCS + c8) = v;
    }
}

// ---- main (round 6): WAVE-PRIVATE ROWS, NO MID-TILE BARRIER.
//      4 waves x 16 rows each; every wave computes the FULL 64-col tile for its
//      rows, so P never crosses waves: the P transpose goes through a private
//      LDS scratch with only a compiler-inserted lgkmcnt (same-wave dep), no
//      s_barrier. One __syncthreads per tile (DMA buffer swap). Waves drift ->
//      wave A's MFMA overlaps wave B's select/exp VALU. 256 threads, LDS
//      80896 B -> 2 independent blocks/CU (second decoupling level), grid 512.
//      Rationale: R0 vs R3/R4 showed occupancy alone gains 0% because all
//      waves sit in one barrier domain marching in phase lockstep (MfmaUtil
//      16%, VALUBusy 27%, nothing saturated).
//      Split-m combine is now via fp32 atomicAdd (8 adds/cell, low contention)
//      so NSPLIT=8 doesn't need a 16.8 MB Opart. ----
__global__ __launch_bounds__(256, 2) void gat_flash_kernel(
    const float* __restrict__ hidden,        // fp32 (for Q fragments)
    const unsigned short* __restrict__ Hpack,
    const int*   __restrict__ adj,           // [NN][NN] int32
    const float* __restrict__ W,
    const float* __restrict__ bvec,
    float*       __restrict__ Onum,          // [NN][DIM] fp32, pre-zeroed
    float*       __restrict__ lsum)          // [NN] fp32, pre-zeroed
{
    __shared__ __align__(16) unsigned short HH[2][TILE_USH];   // 71680 B
    __shared__ __align__(16) unsigned short Plc[4][16 * PST];  // 9216 B

    const int tid  = threadIdx.x;
    const int w    = tid >> 6;         // 0..3: wave = 16-row group
    const int lane = tid & 63;
    const int g    = lane >> 4;
    const int l15  = lane & 15;
    const int blk  = blockIdx.x;
    const int nbr  = blk >> 3;         // 0..63 row-group of 64
    const int q8   = blk & 7;          // 0..7 column eighth
    const int n0   = nbr * TN;
    const int gt0  = q8 * NTILES;      // first global tile (of 64)
    const int lofs = lane * 16;

    const float b0 = bvec[0], b1 = bvec[1], b2 = bvec[2], b3 = bvec[3];

    // ---- prologue: DMA tile 0 -> HH[0]; overlaps Af build below ----
    {
        const char* src = (const char*)(Hpack + (size_t)gt0 * TILE_USH);
        char* dst = (char*)&HH[0][0];
        #pragma unroll
        for (int it = 0; it < 9; ++it) {
            int chunk = it * 4 + w;
            if (chunk < TILE_CHUNKS)
                dma16(src + chunk * 1024 + lofs, dst + chunk * 1024);
        }
    }

    // ---- Af built directly from global (h ⊙ W_k), no LDS staging, no barrier.
    //      A-frag: lane(g,l15) = row l15 of wave's 16, K-elems ks*32+8g..+8 ----
    bf16x8 Af[4][4];
    {
        const int qrow = n0 + w * 16 + l15;
        #pragma unroll
        for (int ks = 0; ks < 4; ++ks) {
            const float* hp = hidden + (size_t)qrow * DIM + ks * 32 + 8 * g;
            float4 h0 = *(const float4*)(hp);
            float4 h1 = *(const float4*)(hp + 4);
            #pragma unroll
            for (int k = 0; k < 4; ++k) {
                const float* wp = W + k * DIM + ks * 32 + 8 * g;
                float4 w0 = *(const float4*)(wp);
                float4 w1 = *(const float4*)(wp + 4);
                bf16x8 a;
                a[0] = (short)f2bf(h0.x * w0.x); a[1] = (short)f2bf(h0.y * w0.y);
                a[2] = (short)f2bf(h0.z * w0.z); a[3] = (short)f2bf(h0.w * w0.w);
                a[4] = (short)f2bf(h1.x * w1.x); a[5] = (short)f2bf(h1.y * w1.y);
                a[6] = (short)f2bf(h1.z * w1.z); a[7] = (short)f2bf(h1.w * w1.w);
                Af[k][ks] = a;
            }
        }
    }

    float lrow[4] = {0.f, 0.f, 0.f, 0.f};
    f32x4 Oacc[8];
    #pragma unroll
    for (int dt = 0; dt < 8; ++dt) Oacc[dt] = (f32x4){0.f, 0.f, 0.f, 0.f};

    // adj codes for tile 0: 16 coalesced int loads/lane (rows 4g+t, cols ch*16+l15)
    const size_t arow = (size_t)(n0 + w * 16 + 4 * g) * NN;
    int avc[16], avn[16];
    #pragma unroll
    for (int ch = 0; ch < 4; ++ch)
        #pragma unroll
        for (int t = 0; t < 4; ++t)
            avc[ch * 4 + t] = adj[arow + (size_t)t * NN + gt0 * TM + ch * 16 + l15];

    __syncthreads();   // drains tile-0 DMA (vmcnt); only barrier before loop

    unsigned short* Pw = &Plc[w][0];   // wave-private P scratch [16][PST]

    for (int tile = 0; tile < NTILES; ++tile) {
        const int cur = tile & 1;
        const int nxt = cur ^ 1;

        // ---- issue next-tile DMA; stays in flight all tile ----
        if (tile + 1 < NTILES) {
            const char* src = (const char*)(Hpack + (size_t)(gt0 + tile + 1) * TILE_USH);
            char* dst = (char*)&HH[nxt][0];
            #pragma unroll
            for (int it = 0; it < 9; ++it) {
                int chunk = it * 4 + w;
                if (chunk < TILE_CHUNKS)
                    dma16(src + chunk * 1024 + lofs, dst + chunk * 1024);
            }
        }

        // ---- QK + select + exp, one 16-col ch slice at a time (S live = 16 regs)
        #pragma unroll
        for (int ch = 0; ch < 4; ++ch) {
            f32x4 S[4];
            #pragma unroll
            for (int k = 0; k < 4; ++k) S[k] = (f32x4){0.f, 0.f, 0.f, 0.f};
            #pragma unroll
            for (int ks = 0; ks < 4; ++ks) {
                bf16x8 B = *(const bf16x8*)&HH[cur][(ch * 16 + l15) * HRS + ks * 32 + 8 * g];
                #pragma unroll
                for (int k = 0; k < 4; ++k)
                    S[k] = __builtin_amdgcn_mfma_f32_16x16x32_bf16(Af[k][ks], B, S[k], 0, 0, 0);
            }
            #pragma unroll
            for (int t = 0; t < 4; ++t) {
                int a = avc[ch * 4 + t];
                float s = S[0][t] + b0;
                s = (a == 2) ? S[1][t] + b1 : s;
                s = (a == 3) ? S[2][t] + b2 : s;
                s = (a == 4) ? S[3][t] + b3 : s;
                float e = fmaxf(s, 0.2f * s);
                float p = __expf(e);           // no-max softmax; scores bounded
                p = (a == 0) ? 0.f : p;
                lrow[t] += p;
                Pw[(4 * g + t) * PST + ch * 16 + l15] = f2bf(p);
            }
        }

        // ---- adj prefetch for next tile (hidden by PV + next QK) ----
        if (tile + 1 < NTILES) {
            #pragma unroll
            for (int ch = 0; ch < 4; ++ch)
                #pragma unroll
                for (int t = 0; t < 4; ++t)
                    avn[ch * 4 + t] = adj[arow + (size_t)t * NN + (size_t)(gt0 + tile + 1) * TM + ch * 16 + l15];
        }

        // ---- PV: NO barrier — Pw is wave-private; the compiler orders the
        //      Plc write->read with lgkmcnt. O[q][d] over full d=128. ----
        #pragma unroll
        for (int kc = 0; kc < 2; ++kc) {
            bf16x8 Pa = *(const bf16x8*)&Pw[l15 * PST + kc * 32 + 8 * g];
            #pragma unroll
            for (int dt = 0; dt < 8; ++dt) {
                bf16x8 Bv = *(const bf16x8*)&HH[cur][HROW_USH + (dt * 16 + l15) * HCS + kc * 32 + 8 * g];
                Oacc[dt] = __builtin_amdgcn_mfma_f32_16x16x32_bf16(Pa, Bv, Oacc[dt], 0, 0, 0);
            }
        }

        #pragma unroll
        for (int i = 0; i < 16; ++i) avc[i] = avn[i];
        __syncthreads();   // vmcnt(0) drain == "HH[nxt] staged"; buffer swap
    }

    // ---- epilogue: rows are wave-private -> no cross-wave reduction.
    //      l: shuffle-reduce over l15; O: 8 adds/cell via fp32 atomics ----
    #pragma unroll
    for (int t = 0; t < 4; ++t) {
        float v = lrow[t];
        v += __shfl_xor(v, 1); v += __shfl_xor(v, 2);
        v += __shfl_xor(v, 4); v += __shfl_xor(v, 8);
        if (l15 == 0) atomicAdd(&lsum[n0 + w * 16 + 4 * g + t], v);
    }
    const int orow0 = n0 + w * 16 + 4 * g;
    #pragma unroll
    for (int dt = 0; dt < 8; ++dt)
        #pragma unroll
        for (int t = 0; t < 4; ++t)
            atomicAdd(&Onum[(size_t)(orow0 + t) * DIM + dt * 16 + l15], Oacc[dt][t]);
}

// ---- combine: trivial divide ----
__global__ __launch_bounds__(256) void combine_kernel(
    const float* __restrict__ Onum, const float* __restrict__ lsum,
    float* __restrict__ out)
{
    int idx = blockIdx.x * 256 + threadIdx.x;
    out[idx] = Onum[idx] / lsum[idx >> 7];
}

extern "C" void kernel_launch(void* const* d_in, const int* in_sizes, int n_in,
                              void* d_out, int out_size, void* d_ws, size_t ws_size,
                              hipStream_t stream) {
    const float* hidden = (const float*)d_in[0];
    const int*   adj    = (const int*)d_in[1];
    const float* W      = (const float*)d_in[2];
    const float* b      = (const float*)d_in[3];
    float* out = (float*)d_out;

    char* ws = (char*)d_ws;
    unsigned short* Hpack = (unsigned short*)ws;                 // 2.29 MB
    float* Onum = (float*)(ws + (4u << 20));                     // 2 MB
    float* lsum = (float*)(ws + (6u << 20));                     // 16 KB
    // zero the atomic accumulators (graph-capturable memset node)
    hipMemsetAsync(ws + (4u << 20), 0, (size_t)NN * DIM * 4 + (2u << 20) - (size_t)NN * DIM * 4 + NN * 4, stream);

    prep_pack_kernel<<<(NN / TM) * 8, 256, 0, stream>>>(hidden, Hpack);
    gat_flash_kernel<<<(NN / TN) * NSPLIT, 256, 0, stream>>>(hidden, Hpack, adj, W, b, Onum, lsum);
    combine_kernel<<<NN * DIM / 256, 256, 0, stream>>>(Onum, lsum, out);
}